// Round 1
// baseline (351.748 us; speedup 1.0000x reference)
//
#include <hip/hip_runtime.h>
#include <hip/hip_bf16.h>
#include <math.h>
#include <stdint.h>

// Problem constants (B=2, S=2048 -> T=4096 tokens)
#define TOKENS 4096
#define HDIM   768
#define FFDIM  1536
#define NEXP   8

typedef __attribute__((ext_vector_type(8))) short bf16x8;   // 8 bf16 = 4 VGPRs
typedef __attribute__((ext_vector_type(4))) float f32x4;    // MFMA accumulator

// round-to-nearest-even f32 -> bf16 (bit pattern)
__device__ __forceinline__ unsigned short f2bf(float f) {
    union { float f; uint32_t u; } c; c.f = f;
    uint32_t u = c.u;
    uint32_t r = (u + 0x7FFFu + ((u >> 16) & 1u)) >> 16;
    return (unsigned short)r;
}

// async global->LDS, 16B per lane; LDS dest is wave-uniform base + lane*16
__device__ __forceinline__ void gload_lds16(const void* g, void* l) {
    __builtin_amdgcn_global_load_lds(
        (const __attribute__((address_space(1))) void*)g,
        (__attribute__((address_space(3))) void*)l, 16, 0, 0);
}

// ---------------------------------------------------------------------------
// zero the dense-out region of d_out, and the 8 expert counters
__global__ void zero_init(float* __restrict__ outp, int n, int* __restrict__ counts) {
    int i = blockIdx.x * blockDim.x + threadIdx.x;
    if (i < NEXP) counts[i] = 0;
    int stride = gridDim.x * blockDim.x;
    for (int j = i; j < n; j += stride) outp[j] = 0.f;
}

// fp32 -> bf16 cast, vectorized float4 -> ushort4 (n4 = n/4 groups)
__global__ void cast_bf16(const float* __restrict__ src,
                          unsigned short* __restrict__ dst, int n4) {
    int stride = gridDim.x * blockDim.x;
    for (int i = blockIdx.x * blockDim.x + threadIdx.x; i < n4; i += stride) {
        float4 v = ((const float4*)src)[i];
        ushort4 o;
        o.x = f2bf(v.x); o.y = f2bf(v.y); o.z = f2bf(v.z); o.w = f2bf(v.w);
        ((ushort4*)dst)[i] = o;
    }
}

// ---------------------------------------------------------------------------
// Gating: one wave per token. fp32 logits (checked output!), top-2 softmax,
// atomic append (entry = t*2+k, gate) to per-expert lists.
__global__ __launch_bounds__(64) void gating(
    const float* __restrict__ x, const float* __restrict__ gw,
    float* __restrict__ logits, int* __restrict__ counts,
    int* __restrict__ entries, float* __restrict__ gates)
{
    int t = blockIdx.x;
    int lane = threadIdx.x;
    const float* xt = x + (size_t)t * HDIM;
    float acc[NEXP];
#pragma unroll
    for (int e = 0; e < NEXP; e++) acc[e] = 0.f;
    for (int i = lane; i < HDIM; i += 64) {
        float xv = xt[i];
#pragma unroll
        for (int e = 0; e < NEXP; e++) acc[e] += xv * gw[e * HDIM + i];
    }
#pragma unroll
    for (int e = 0; e < NEXP; e++) {
        float v = acc[e];
#pragma unroll
        for (int off = 32; off > 0; off >>= 1) v += __shfl_down(v, off);
        acc[e] = v;   // valid on lane 0
    }
    if (lane == 0) {
#pragma unroll
        for (int e = 0; e < NEXP; e++) logits[(size_t)t * NEXP + e] = acc[e];
        int i0 = 0; float v0 = acc[0];
#pragma unroll
        for (int e = 1; e < NEXP; e++) if (acc[e] > v0) { v0 = acc[e]; i0 = e; }
        int i1 = -1; float v1 = -3.4e38f;
#pragma unroll
        for (int e = 0; e < NEXP; e++) if (e != i0 && acc[e] > v1) { v1 = acc[e]; i1 = e; }
        float g0 = 1.f / (1.f + expf(v1 - v0));   // softmax over top-2 (v0 >= v1)
        float g1 = 1.f - g0;
        int s0 = atomicAdd(&counts[i0], 1);
        entries[i0 * TOKENS + s0] = t * 2;
        gates[i0 * TOKENS + s0] = g0;
        int s1 = atomicAdd(&counts[i1], 1);
        entries[i1 * TOKENS + s1] = t * 2 + 1;
        gates[i1 * TOKENS + s1] = g1;
    }
}

// ---------------------------------------------------------------------------
// Routed GEMM: C[rows of expert-e list, 64-col tile] = gathered-A @ B^T
//   A rows gathered via entry list (IS_FC: x_bf row = entry>>1; else hmid row = entry)
//   B is [N][K] row-major (w_fc: [FF][H], w_proj: [H][FF]) — natural B^T form.
// 64x64 tile, BK=32, 4 waves each computing a 16-row x 64-col strip via
// 4x mfma_f32_16x16x32_bf16. Staging: global_load_lds 16B/lane with XOR
// K-segment swizzle (seg ^= (row>>1)&3) so frag ds_read_b128 is conflict-free.
template<int KD, int ND, bool IS_FC>
__global__ __launch_bounds__(256) void moe_gemm(
    const unsigned short* __restrict__ Asrc,
    const unsigned short* __restrict__ Bsrc,
    const int* __restrict__ counts,
    const int* __restrict__ entries,
    const float* __restrict__ gates,
    unsigned short* __restrict__ hmid,
    float* __restrict__ outp)
{
    int e = blockIdx.z;
    int n_e = counts[e];
    int rowTile = blockIdx.y;
    if (rowTile * 64 >= n_e) return;
    int n0 = blockIdx.x * 64;

    __shared__ __align__(16) unsigned short sA[64 * 32];
    __shared__ __align__(16) unsigned short sB[64 * 32];

    int tid = threadIdx.x;
    int w = tid >> 6;          // wave 0..3
    int l = tid & 63;          // lane

    const int* lst = entries + e * TOKENS;

    // ---- staging addressing: wave w stages tile rows [w*16, w*16+16) of A and B
    int rL   = (w << 4) + (l >> 2);        // tile row staged by this lane
    int p    = l & 3;                      // 16B segment position in LDS row
    int sseg = p ^ ((rL >> 1) & 3);        // swizzled global K-segment to fetch

    int lrow = rowTile * 64 + rL;
    int idx  = lrow < n_e ? lrow : n_e - 1;  // clamp (content discarded in epilogue)
    int ent  = lst[idx];
    int arow = IS_FC ? (ent >> 1) : ent;

    const unsigned short* Ab = Asrc + (size_t)arow * KD + sseg * 8;
    const unsigned short* Bb = Bsrc + (size_t)e * ND * KD + (size_t)(n0 + rL) * KD + sseg * 8;
    unsigned short* sAw = sA + w * 512;    // wave-uniform LDS dest base
    unsigned short* sBw = sB + w * 512;

    // ---- fragment addressing (A: row=lo,k=q*8+j ; B^T: n=lo,k=q*8+j ; D: col=lo,row=q*4+r)
    int lo = l & 15;
    int q  = l >> 4;
    int pa = q ^ ((lo >> 1) & 3);          // swizzled LDS segment holding K-seg q
    int aOff     = w * 512 + lo * 32 + pa * 8;
    int bOffBase = lo * 32 + pa * 8;

    f32x4 acc[4];
#pragma unroll
    for (int i = 0; i < 4; i++) acc[i] = (f32x4){0.f, 0.f, 0.f, 0.f};

    for (int k0 = 0; k0 < KD; k0 += 32) {
        gload_lds16(Ab + k0, sAw);
        gload_lds16(Bb + k0, sBw);
        __syncthreads();                    // compiler drains vmcnt before barrier
        bf16x8 va = *(const bf16x8*)(sA + aOff);
#pragma unroll
        for (int nt = 0; nt < 4; nt++) {
            bf16x8 vb = *(const bf16x8*)(sB + nt * 512 + bOffBase);
            acc[nt] = __builtin_amdgcn_mfma_f32_16x16x32_bf16(va, vb, acc[nt], 0, 0, 0);
        }
        __syncthreads();
    }

    // ---- epilogue
#pragma unroll
    for (int r = 0; r < 4; r++) {
        int orow = rowTile * 64 + (w << 4) + q * 4 + r;   // slot in expert list
        if (orow < n_e) {
            int oent = lst[orow];
            if (IS_FC) {
                size_t rowid = (size_t)oent;              // hmid row = t*2+k
#pragma unroll
                for (int nt = 0; nt < 4; nt++) {
                    float v = acc[nt][r];
                    v = 0.5f * v * (1.f + erff(v * 0.70710678118654752f));  // exact gelu
                    hmid[rowid * FFDIM + n0 + nt * 16 + lo] = f2bf(v);
                }
            } else {
                int token = oent >> 1;
                float g = gates[e * TOKENS + orow];
#pragma unroll
                for (int nt = 0; nt < 4; nt++) {
                    atomicAdd(&outp[(size_t)token * HDIM + n0 + nt * 16 + lo],
                              acc[nt][r] * g);
                }
            }
        }
    }
}

// ---------------------------------------------------------------------------
extern "C" void kernel_launch(void* const* d_in, const int* in_sizes, int n_in,
                              void* d_out, int out_size, void* d_ws, size_t ws_size,
                              hipStream_t stream) {
    const float* x     = (const float*)d_in[0];   // [T, H]
    const float* gw    = (const float*)d_in[1];   // [E, H]
    const float* wfc   = (const float*)d_in[2];   // [E, FF, H]
    const float* wproj = (const float*)d_in[3];   // [E, H, FF]
    float* outp   = (float*)d_out;                       // [T*H]
    float* logits = outp + (size_t)TOKENS * HDIM;        // [T*E]

    char* ws = (char*)d_ws;
    int*   counts  = (int*)ws;                                   // 8 ints
    int*   entries = (int*)(ws + 256);                           // [E][T]
    float* gates   = (float*)(ws + 256 + NEXP * TOKENS * 4);     // [E][T]
    size_t off = 256 + 2ull * NEXP * TOKENS * 4;
    unsigned short* x_bf   = (unsigned short*)(ws + off); off += (size_t)TOKENS * HDIM * 2;
    unsigned short* wfc_bf = (unsigned short*)(ws + off); off += (size_t)NEXP * FFDIM * HDIM * 2;
    unsigned short* wpj_bf = (unsigned short*)(ws + off); off += (size_t)NEXP * HDIM * FFDIM * 2;
    unsigned short* hmid   = (unsigned short*)(ws + off);        // [2T][FF] bf16

    zero_init<<<2048, 256, 0, stream>>>(outp, TOKENS * HDIM, counts);
    cast_bf16<<<1536, 256, 0, stream>>>(x, x_bf, TOKENS * HDIM / 4);
    cast_bf16<<<2048, 256, 0, stream>>>(wfc, wfc_bf, NEXP * FFDIM * HDIM / 4);
    cast_bf16<<<2048, 256, 0, stream>>>(wproj, wpj_bf, NEXP * HDIM * FFDIM / 4);
    gating<<<TOKENS, 64, 0, stream>>>(x, gw, logits, counts, entries, gates);
    moe_gemm<HDIM, FFDIM, true ><<<dim3(FFDIM / 64, 64, NEXP), 256, 0, stream>>>(
        x_bf, wfc_bf, counts, entries, gates, hmid, outp);
    moe_gemm<FFDIM, HDIM, false><<<dim3(HDIM / 64, 64, NEXP), 256, 0, stream>>>(
        hmid, wpj_bf, counts, entries, gates, hmid, outp);
}

// Round 2
// 264.835 us; speedup vs baseline: 1.3282x; 1.3282x over previous
//
#include <hip/hip_runtime.h>
#include <hip/hip_bf16.h>
#include <math.h>
#include <stdint.h>

// Problem constants (B=2, S=2048 -> T=4096 tokens)
#define TOKENS 4096
#define HDIM   768
#define FFDIM  1536
#define NEXP   8

typedef __attribute__((ext_vector_type(8))) short bf16x8;   // 8 bf16 = 4 VGPRs
typedef __attribute__((ext_vector_type(4))) float f32x4;    // MFMA accumulator

// round-to-nearest-even f32 -> bf16 (bit pattern)
__device__ __forceinline__ unsigned short f2bf(float f) {
    union { float f; uint32_t u; } c; c.f = f;
    uint32_t u = c.u;
    uint32_t r = (u + 0x7FFFu + ((u >> 16) & 1u)) >> 16;
    return (unsigned short)r;
}

// async global->LDS, 16B per lane; LDS dest is wave-uniform base + lane*16
__device__ __forceinline__ void gload_lds16(const void* g, void* l) {
    __builtin_amdgcn_global_load_lds(
        (const __attribute__((address_space(1))) void*)g,
        (__attribute__((address_space(3))) void*)l, 16, 0, 0);
}

// ---------------------------------------------------------------------------
// zero the dense-out region of d_out
__global__ void zero_init(float* __restrict__ outp, int n) {
    int i = blockIdx.x * blockDim.x + threadIdx.x;
    int stride = gridDim.x * blockDim.x;
    for (int j = i; j < n; j += stride) outp[j] = 0.f;
}

// fp32 -> bf16 cast, vectorized float4 -> ushort4 (n4 = n/4 groups)
__global__ void cast_bf16(const float* __restrict__ src,
                          unsigned short* __restrict__ dst, int n4) {
    int stride = gridDim.x * blockDim.x;
    for (int i = blockIdx.x * blockDim.x + threadIdx.x; i < n4; i += stride) {
        float4 v = ((const float4*)src)[i];
        ushort4 o;
        o.x = f2bf(v.x); o.y = f2bf(v.y); o.z = f2bf(v.z); o.w = f2bf(v.w);
        ((ushort4*)dst)[i] = o;
    }
}

// ---------------------------------------------------------------------------
// Gating: one wave per token (4 tokens / 256-thread block). fp32 logits
// (checked output!), top-2 softmax, NO atomics — writes per-token dense
// tok_e[t*2+k] / tok_g[t*2+k].
__global__ __launch_bounds__(256) void gating(
    const float* __restrict__ x, const float* __restrict__ gw,
    float* __restrict__ logits,
    int* __restrict__ tok_e, float* __restrict__ tok_g)
{
    int t = blockIdx.x * 4 + (threadIdx.x >> 6);
    int lane = threadIdx.x & 63;
    const float4* xt = (const float4*)(x + (size_t)t * HDIM);   // 192 float4/token
    const float4* gw4 = (const float4*)gw;                      // [E][192]
    float acc[NEXP];
#pragma unroll
    for (int e = 0; e < NEXP; e++) acc[e] = 0.f;
#pragma unroll
    for (int it = 0; it < 3; it++) {
        int i = lane + it * 64;
        float4 xv = xt[i];
#pragma unroll
        for (int e = 0; e < NEXP; e++) {
            float4 wv = gw4[e * 192 + i];
            acc[e] += xv.x * wv.x + xv.y * wv.y + xv.z * wv.z + xv.w * wv.w;
        }
    }
#pragma unroll
    for (int e = 0; e < NEXP; e++) {
#pragma unroll
        for (int off = 32; off > 0; off >>= 1)
            acc[e] += __shfl_xor(acc[e], off);
    }
    if (lane == 0) {
        float4 l0 = make_float4(acc[0], acc[1], acc[2], acc[3]);
        float4 l1 = make_float4(acc[4], acc[5], acc[6], acc[7]);
        float4* lp = (float4*)(logits + (size_t)t * NEXP);
        lp[0] = l0; lp[1] = l1;
        int i0 = 0; float v0 = acc[0];
#pragma unroll
        for (int e = 1; e < NEXP; e++) if (acc[e] > v0) { v0 = acc[e]; i0 = e; }
        int i1 = -1; float v1 = -3.4e38f;
#pragma unroll
        for (int e = 0; e < NEXP; e++) if (e != i0 && acc[e] > v1) { v1 = acc[e]; i1 = e; }
        float g0 = 1.f / (1.f + expf(v1 - v0));   // softmax over top-2 (v0 >= v1)
        tok_e[t * 2] = i0; tok_e[t * 2 + 1] = i1;
        tok_g[t * 2] = g0; tok_g[t * 2 + 1] = 1.f - g0;
    }
}

// ---------------------------------------------------------------------------
// Build per-expert routed lists deterministically (no global atomics).
// Single block, 1024 threads, 8 (token,k) entries per thread. Histogram is
// packed 16-bit x 4 experts in each of two u64s; Hillis-Steele inclusive
// scan across threads; then in-order scatter using the exclusive prefix.
__global__ __launch_bounds__(1024) void build_lists(
    const int* __restrict__ tok_e, const float* __restrict__ tok_g,
    int* __restrict__ counts, int* __restrict__ entries,
    float* __restrict__ gates)
{
    __shared__ unsigned long long slo[1024], shi[1024];
    int tid = threadIdx.x;
    int eL[8]; float gL[8];
    int4 ea = ((const int4*)tok_e)[tid * 2];
    int4 eb = ((const int4*)tok_e)[tid * 2 + 1];
    float4 ga = ((const float4*)tok_g)[tid * 2];
    float4 gb = ((const float4*)tok_g)[tid * 2 + 1];
    eL[0] = ea.x; eL[1] = ea.y; eL[2] = ea.z; eL[3] = ea.w;
    eL[4] = eb.x; eL[5] = eb.y; eL[6] = eb.z; eL[7] = eb.w;
    gL[0] = ga.x; gL[1] = ga.y; gL[2] = ga.z; gL[3] = ga.w;
    gL[4] = gb.x; gL[5] = gb.y; gL[6] = gb.z; gL[7] = gb.w;

    unsigned long long clo = 0, chi = 0;
#pragma unroll
    for (int j = 0; j < 8; j++) {
        int e = eL[j];
        unsigned long long one = 1ull << ((e & 3) * 16);
        if (e < 4) clo += one; else chi += one;
    }
    slo[tid] = clo; shi[tid] = chi;
    __syncthreads();
    for (int s = 1; s < 1024; s <<= 1) {
        unsigned long long vlo = 0, vhi = 0;
        if (tid >= s) { vlo = slo[tid - s]; vhi = shi[tid - s]; }
        __syncthreads();
        slo[tid] += vlo; shi[tid] += vhi;
        __syncthreads();
    }
    unsigned long long rlo = slo[tid] - clo;   // exclusive prefix (running)
    unsigned long long rhi = shi[tid] - chi;
    if (tid == 0) {
        unsigned long long tlo = slo[1023], thi = shi[1023];
#pragma unroll
        for (int e = 0; e < 4; e++) {
            counts[e]     = (int)((tlo >> (e * 16)) & 0xFFFF);
            counts[e + 4] = (int)((thi >> (e * 16)) & 0xFFFF);
        }
    }
#pragma unroll
    for (int j = 0; j < 8; j++) {
        int e = eL[j];
        int sh = (e & 3) * 16;
        unsigned long long one = 1ull << sh;
        int slot;
        if (e < 4) { slot = (int)((rlo >> sh) & 0xFFFF); rlo += one; }
        else       { slot = (int)((rhi >> sh) & 0xFFFF); rhi += one; }
        entries[e * TOKENS + slot] = tid * 8 + j;   // = t*2+k
        gates[e * TOKENS + slot]   = gL[j];
    }
}

// ---------------------------------------------------------------------------
// Routed GEMM: C[rows of expert-e list, 64-col tile] = gathered-A @ B^T
//   A rows gathered via entry list (IS_FC: x_bf row = entry>>1; else hmid row = entry)
//   B is [N][K] row-major (w_fc: [FF][H], w_proj: [H][FF]) — natural B^T form.
// 64x64 tile, BK=32, 4 waves each computing a 16-row x 64-col strip via
// 4x mfma_f32_16x16x32_bf16. Staging: global_load_lds 16B/lane with XOR
// K-segment swizzle (seg ^= (row>>1)&3) so frag ds_read_b128 is conflict-free.
template<int KD, int ND, bool IS_FC>
__global__ __launch_bounds__(256) void moe_gemm(
    const unsigned short* __restrict__ Asrc,
    const unsigned short* __restrict__ Bsrc,
    const int* __restrict__ counts,
    const int* __restrict__ entries,
    const float* __restrict__ gates,
    unsigned short* __restrict__ hmid,
    float* __restrict__ outp)
{
    int e = blockIdx.z;
    int n_e = counts[e];
    int rowTile = blockIdx.y;
    if (rowTile * 64 >= n_e) return;
    int n0 = blockIdx.x * 64;

    __shared__ __align__(16) unsigned short sA[64 * 32];
    __shared__ __align__(16) unsigned short sB[64 * 32];

    int tid = threadIdx.x;
    int w = tid >> 6;          // wave 0..3
    int l = tid & 63;          // lane

    const int* lst = entries + e * TOKENS;

    // ---- staging addressing: wave w stages tile rows [w*16, w*16+16) of A and B
    int rL   = (w << 4) + (l >> 2);        // tile row staged by this lane
    int p    = l & 3;                      // 16B segment position in LDS row
    int sseg = p ^ ((rL >> 1) & 3);        // swizzled global K-segment to fetch

    int lrow = rowTile * 64 + rL;
    int idx  = lrow < n_e ? lrow : n_e - 1;  // clamp (content discarded in epilogue)
    int ent  = lst[idx];
    int arow = IS_FC ? (ent >> 1) : ent;

    const unsigned short* Ab = Asrc + (size_t)arow * KD + sseg * 8;
    const unsigned short* Bb = Bsrc + (size_t)e * ND * KD + (size_t)(n0 + rL) * KD + sseg * 8;
    unsigned short* sAw = sA + w * 512;    // wave-uniform LDS dest base
    unsigned short* sBw = sB + w * 512;

    // ---- fragment addressing (A: row=lo,k=q*8+j ; B^T: n=lo,k=q*8+j ; D: col=lo,row=q*4+r)
    int lo = l & 15;
    int q  = l >> 4;
    int pa = q ^ ((lo >> 1) & 3);          // swizzled LDS segment holding K-seg q
    int aOff     = w * 512 + lo * 32 + pa * 8;
    int bOffBase = lo * 32 + pa * 8;

    f32x4 acc[4];
#pragma unroll
    for (int i = 0; i < 4; i++) acc[i] = (f32x4){0.f, 0.f, 0.f, 0.f};

    for (int k0 = 0; k0 < KD; k0 += 32) {
        gload_lds16(Ab + k0, sAw);
        gload_lds16(Bb + k0, sBw);
        __syncthreads();                    // compiler drains vmcnt before barrier
        bf16x8 va = *(const bf16x8*)(sA + aOff);
#pragma unroll
        for (int nt = 0; nt < 4; nt++) {
            bf16x8 vb = *(const bf16x8*)(sB + nt * 512 + bOffBase);
            acc[nt] = __builtin_amdgcn_mfma_f32_16x16x32_bf16(va, vb, acc[nt], 0, 0, 0);
        }
        __syncthreads();
    }

    // ---- epilogue
#pragma unroll
    for (int r = 0; r < 4; r++) {
        int orow = rowTile * 64 + (w << 4) + q * 4 + r;   // slot in expert list
        if (orow < n_e) {
            int oent = lst[orow];
            if (IS_FC) {
                size_t rowid = (size_t)oent;              // hmid row = t*2+k
#pragma unroll
                for (int nt = 0; nt < 4; nt++) {
                    float v = acc[nt][r];
                    v = 0.5f * v * (1.f + erff(v * 0.70710678118654752f));  // exact gelu
                    hmid[rowid * FFDIM + n0 + nt * 16 + lo] = f2bf(v);
                }
            } else {
                int token = oent >> 1;
                float g = gates[e * TOKENS + orow];
#pragma unroll
                for (int nt = 0; nt < 4; nt++) {
                    atomicAdd(&outp[(size_t)token * HDIM + n0 + nt * 16 + lo],
                              acc[nt][r] * g);
                }
            }
        }
    }
}

// ---------------------------------------------------------------------------
extern "C" void kernel_launch(void* const* d_in, const int* in_sizes, int n_in,
                              void* d_out, int out_size, void* d_ws, size_t ws_size,
                              hipStream_t stream) {
    const float* x     = (const float*)d_in[0];   // [T, H]
    const float* gw    = (const float*)d_in[1];   // [E, H]
    const float* wfc   = (const float*)d_in[2];   // [E, FF, H]
    const float* wproj = (const float*)d_in[3];   // [E, H, FF]
    float* outp   = (float*)d_out;                       // [T*H]
    float* logits = outp + (size_t)TOKENS * HDIM;        // [T*E]

    char* ws = (char*)d_ws;
    int*   counts  = (int*)ws;                                   // 8 ints
    int*   entries = (int*)(ws + 256);                           // [E][T]
    float* gates   = (float*)(ws + 256 + NEXP * TOKENS * 4);     // [E][T]
    size_t off = 256 + 2ull * NEXP * TOKENS * 4;
    int*   tok_e   = (int*)(ws + off);   off += (size_t)TOKENS * 2 * 4;
    float* tok_g   = (float*)(ws + off); off += (size_t)TOKENS * 2 * 4;
    unsigned short* x_bf   = (unsigned short*)(ws + off); off += (size_t)TOKENS * HDIM * 2;
    unsigned short* wfc_bf = (unsigned short*)(ws + off); off += (size_t)NEXP * FFDIM * HDIM * 2;
    unsigned short* wpj_bf = (unsigned short*)(ws + off); off += (size_t)NEXP * HDIM * FFDIM * 2;
    unsigned short* hmid   = (unsigned short*)(ws + off);        // [2T][FF] bf16

    zero_init<<<2048, 256, 0, stream>>>(outp, TOKENS * HDIM);
    cast_bf16<<<1536, 256, 0, stream>>>(x, x_bf, TOKENS * HDIM / 4);
    cast_bf16<<<2048, 256, 0, stream>>>(wfc, wfc_bf, NEXP * FFDIM * HDIM / 4);
    cast_bf16<<<2048, 256, 0, stream>>>(wproj, wpj_bf, NEXP * HDIM * FFDIM / 4);
    gating<<<TOKENS / 4, 256, 0, stream>>>(x, gw, logits, tok_e, tok_g);
    build_lists<<<1, 1024, 0, stream>>>(tok_e, tok_g, counts, entries, gates);
    moe_gemm<HDIM, FFDIM, true ><<<dim3(FFDIM / 64, 64, NEXP), 256, 0, stream>>>(
        x_bf, wfc_bf, counts, entries, gates, hmid, outp);
    moe_gemm<FFDIM, HDIM, false><<<dim3(HDIM / 64, 64, NEXP), 256, 0, stream>>>(
        hmid, wpj_bf, counts, entries, gates, hmid, outp);
}

// Round 3
// 250.770 us; speedup vs baseline: 1.4027x; 1.0561x over previous
//
#include <hip/hip_runtime.h>
#include <hip/hip_bf16.h>
#include <math.h>
#include <stdint.h>

// Problem constants (B=2, S=2048 -> T=4096 tokens)
#define TOKENS 4096
#define HDIM   768
#define FFDIM  1536
#define NEXP   8

typedef __attribute__((ext_vector_type(8))) short bf16x8;   // 8 bf16 = 4 VGPRs
typedef __attribute__((ext_vector_type(4))) float f32x4;    // MFMA accumulator

// round-to-nearest-even f32 -> bf16 (bit pattern)
__device__ __forceinline__ unsigned short f2bf(float f) {
    union { float f; uint32_t u; } c; c.f = f;
    uint32_t u = c.u;
    uint32_t r = (u + 0x7FFFu + ((u >> 16) & 1u)) >> 16;
    return (unsigned short)r;
}

// async global->LDS, 16B per lane; LDS dest is wave-uniform base + lane*16
__device__ __forceinline__ void gload_lds16(const void* g, void* l) {
    __builtin_amdgcn_global_load_lds(
        (const __attribute__((address_space(1))) void*)g,
        (__attribute__((address_space(3))) void*)l, 16, 0, 0);
}

// ---------------------------------------------------------------------------
// zero the dense-out region of d_out (GEMM2 combines via atomicAdd)
__global__ void zero_init(float* __restrict__ outp, int n) {
    int i = blockIdx.x * blockDim.x + threadIdx.x;
    int stride = gridDim.x * blockDim.x;
    for (int j = i; j < n; j += stride) outp[j] = 0.f;
}

// fp32 -> bf16 cast, vectorized float4 -> ushort4 (n4 = n/4 groups)
__global__ void cast_bf16(const float* __restrict__ src,
                          unsigned short* __restrict__ dst, int n4) {
    int stride = gridDim.x * blockDim.x;
    for (int i = blockIdx.x * blockDim.x + threadIdx.x; i < n4; i += stride) {
        float4 v = ((const float4*)src)[i];
        ushort4 o;
        o.x = f2bf(v.x); o.y = f2bf(v.y); o.z = f2bf(v.z); o.w = f2bf(v.w);
        ((ushort4*)dst)[i] = o;
    }
}

// ---------------------------------------------------------------------------
// Gating: one wave per token (4 tokens / 256-thread block). fp32 logits
// (checked output!), top-2 softmax, no atomics. Also emits the bf16 cast of
// x (fused — gating already reads every element of x).
__global__ __launch_bounds__(256) void gating(
    const float* __restrict__ x, const float* __restrict__ gw,
    float* __restrict__ logits,
    int* __restrict__ tok_e, float* __restrict__ tok_g,
    unsigned short* __restrict__ x_bf)
{
    int t = blockIdx.x * 4 + (threadIdx.x >> 6);
    int lane = threadIdx.x & 63;
    const float4* xt = (const float4*)(x + (size_t)t * HDIM);   // 192 float4/token
    const float4* gw4 = (const float4*)gw;                      // [E][192]
    ushort4* xbt = (ushort4*)(x_bf + (size_t)t * HDIM);
    float acc[NEXP];
#pragma unroll
    for (int e = 0; e < NEXP; e++) acc[e] = 0.f;
#pragma unroll
    for (int it = 0; it < 3; it++) {
        int i = lane + it * 64;
        float4 xv = xt[i];
        ushort4 o;
        o.x = f2bf(xv.x); o.y = f2bf(xv.y); o.z = f2bf(xv.z); o.w = f2bf(xv.w);
        xbt[i] = o;
#pragma unroll
        for (int e = 0; e < NEXP; e++) {
            float4 wv = gw4[e * 192 + i];
            acc[e] += xv.x * wv.x + xv.y * wv.y + xv.z * wv.z + xv.w * wv.w;
        }
    }
#pragma unroll
    for (int e = 0; e < NEXP; e++) {
#pragma unroll
        for (int off = 32; off > 0; off >>= 1)
            acc[e] += __shfl_xor(acc[e], off);
    }
    if (lane == 0) {
        float4 l0 = make_float4(acc[0], acc[1], acc[2], acc[3]);
        float4 l1 = make_float4(acc[4], acc[5], acc[6], acc[7]);
        float4* lp = (float4*)(logits + (size_t)t * NEXP);
        lp[0] = l0; lp[1] = l1;
        int i0 = 0; float v0 = acc[0];
#pragma unroll
        for (int e = 1; e < NEXP; e++) if (acc[e] > v0) { v0 = acc[e]; i0 = e; }
        int i1 = -1; float v1 = -3.4e38f;
#pragma unroll
        for (int e = 0; e < NEXP; e++) if (e != i0 && acc[e] > v1) { v1 = acc[e]; i1 = e; }
        float g0 = 1.f / (1.f + expf(v1 - v0));   // softmax over top-2 (v0 >= v1)
        tok_e[t * 2] = i0; tok_e[t * 2 + 1] = i1;
        tok_g[t * 2] = g0; tok_g[t * 2 + 1] = 1.f - g0;
    }
}

// ---------------------------------------------------------------------------
// Build per-expert routed lists deterministically (no global atomics).
// Single block, 1024 threads, 8 (token,k) entries per thread. Histogram is
// packed 16-bit x 4 experts in each of two u64s; Hillis-Steele inclusive
// scan across threads; then in-order scatter using the exclusive prefix.
// Also emits bases[e] = exclusive scan of counts (global slot offsets).
__global__ __launch_bounds__(1024) void build_lists(
    const int* __restrict__ tok_e, const float* __restrict__ tok_g,
    int* __restrict__ counts, int* __restrict__ bases,
    int* __restrict__ entries, float* __restrict__ gates)
{
    __shared__ unsigned long long slo[1024], shi[1024];
    int tid = threadIdx.x;
    int eL[8]; float gL[8];
    int4 ea = ((const int4*)tok_e)[tid * 2];
    int4 eb = ((const int4*)tok_e)[tid * 2 + 1];
    float4 ga = ((const float4*)tok_g)[tid * 2];
    float4 gb = ((const float4*)tok_g)[tid * 2 + 1];
    eL[0] = ea.x; eL[1] = ea.y; eL[2] = ea.z; eL[3] = ea.w;
    eL[4] = eb.x; eL[5] = eb.y; eL[6] = eb.z; eL[7] = eb.w;
    gL[0] = ga.x; gL[1] = ga.y; gL[2] = ga.z; gL[3] = ga.w;
    gL[4] = gb.x; gL[5] = gb.y; gL[6] = gb.z; gL[7] = gb.w;

    unsigned long long clo = 0, chi = 0;
#pragma unroll
    for (int j = 0; j < 8; j++) {
        int e = eL[j];
        unsigned long long one = 1ull << ((e & 3) * 16);
        if (e < 4) clo += one; else chi += one;
    }
    slo[tid] = clo; shi[tid] = chi;
    __syncthreads();
    for (int s = 1; s < 1024; s <<= 1) {
        unsigned long long vlo = 0, vhi = 0;
        if (tid >= s) { vlo = slo[tid - s]; vhi = shi[tid - s]; }
        __syncthreads();
        slo[tid] += vlo; shi[tid] += vhi;
        __syncthreads();
    }
    unsigned long long rlo = slo[tid] - clo;   // exclusive prefix (running)
    unsigned long long rhi = shi[tid] - chi;
    if (tid == 0) {
        unsigned long long tlo = slo[1023], thi = shi[1023];
        int c[8];
#pragma unroll
        for (int e = 0; e < 4; e++) {
            c[e]     = (int)((tlo >> (e * 16)) & 0xFFFF);
            c[e + 4] = (int)((thi >> (e * 16)) & 0xFFFF);
        }
        int b = 0;
#pragma unroll
        for (int e = 0; e < NEXP; e++) { counts[e] = c[e]; bases[e] = b; b += c[e]; }
    }
#pragma unroll
    for (int j = 0; j < 8; j++) {
        int e = eL[j];
        int sh = (e & 3) * 16;
        unsigned long long one = 1ull << sh;
        int slot;
        if (e < 4) { slot = (int)((rlo >> sh) & 0xFFFF); rlo += one; }
        else       { slot = (int)((rhi >> sh) & 0xFFFF); rhi += one; }
        entries[e * TOKENS + slot] = tid * 8 + j;   // = t*2+k
        gates[e * TOKENS + slot]   = gL[j];
    }
}

// ---------------------------------------------------------------------------
// Routed GEMM, 128x128 tile, BK=32 (m93/m97 structure). 4 waves in 2x2; each
// wave computes a 64x64 sub-tile via 4x4 mfma_f32_16x16x32_bf16 (16 MFMA +
// 8 ds_read_b128 per K-step). Staging: global_load_lds 16B/lane, XOR
// K-segment swizzle (seg ^= (row>>1)&3) -> verified 0 LDS bank conflicts.
//   IS_FC:  A = x_bf gathered via entry list (row = entry>>1), out = gelu ->
//           hmid[base[e]+slot][ND] (slot-compacted, so GEMM2 reads it dense)
//   !IS_FC: A = hmid[base[e]+row] contiguous, out = atomicAdd(gate * acc)
template<int KD, int ND, bool IS_FC>
__global__ __launch_bounds__(256) void moe_gemm(
    const unsigned short* __restrict__ Asrc,
    const unsigned short* __restrict__ Bsrc,    // [E][ND][KD] (B^T form)
    const int* __restrict__ counts,
    const int* __restrict__ bases,
    const int* __restrict__ entries,
    const float* __restrict__ gates,
    unsigned short* __restrict__ hmid,
    float* __restrict__ outp)
{
    int e = blockIdx.z;
    int n_e = counts[e];
    int rowTile = blockIdx.y;
    if (rowTile * 128 >= n_e) return;
    int ebase = bases[e];
    int n0 = blockIdx.x * 128;

    __shared__ __align__(16) unsigned short sA[128 * 32];
    __shared__ __align__(16) unsigned short sB[128 * 32];

    int tid = threadIdx.x;
    int w = tid >> 6;          // wave 0..3
    int l = tid & 63;          // lane
    const int* lst = entries + e * TOKENS;

    // ---- staging: wave w stages tile rows [w*32, w*32+32) of A and B as two
    // 16-row chunks (chunks 2w, 2w+1); lane covers row (l>>2), 16B seg (l&3).
    int r0 = w * 32 + (l >> 2);
    int r1 = r0 + 16;
    int p  = l & 3;
    int ss0 = p ^ ((r0 >> 1) & 3);         // swizzled global K-segment
    int ss1 = p ^ ((r1 >> 1) & 3);

    int lr0 = rowTile * 128 + r0;
    int lr1 = rowTile * 128 + r1;
    int id0 = lr0 < n_e ? lr0 : n_e - 1;   // clamp (discarded in epilogue)
    int id1 = lr1 < n_e ? lr1 : n_e - 1;
    size_t arow0, arow1;
    if (IS_FC) { arow0 = (size_t)(lst[id0] >> 1); arow1 = (size_t)(lst[id1] >> 1); }
    else       { arow0 = (size_t)(ebase + id0);   arow1 = (size_t)(ebase + id1);   }

    const unsigned short* Ag0 = Asrc + arow0 * KD + ss0 * 8;
    const unsigned short* Ag1 = Asrc + arow1 * KD + ss1 * 8;
    const unsigned short* Bg0 = Bsrc + ((size_t)e * ND + n0 + r0) * KD + ss0 * 8;
    const unsigned short* Bg1 = Bsrc + ((size_t)e * ND + n0 + r1) * KD + ss1 * 8;
    unsigned short* sA0 = sA + (2 * w)     * 512;   // wave-uniform LDS bases
    unsigned short* sA1 = sA + (2 * w + 1) * 512;
    unsigned short* sB0 = sB + (2 * w)     * 512;
    unsigned short* sB1 = sB + (2 * w + 1) * 512;

    // ---- fragment addressing (A: row=lo,k=q*8+j ; B^T: n=lo,k=q*8+j)
    int lo = l & 15;
    int q  = l >> 4;
    int wr = w >> 1, wc = w & 1;
    int aOff[4], bOff[4];
#pragma unroll
    for (int i = 0; i < 4; i++) {
        int m = wr * 64 + i * 16 + lo;
        aOff[i] = m * 32 + (q ^ ((m >> 1) & 3)) * 8;
        int n = wc * 64 + i * 16 + lo;
        bOff[i] = n * 32 + (q ^ ((n >> 1) & 3)) * 8;
    }

    f32x4 acc[4][4];
#pragma unroll
    for (int i = 0; i < 4; i++)
#pragma unroll
        for (int j = 0; j < 4; j++) acc[i][j] = (f32x4){0.f, 0.f, 0.f, 0.f};

    for (int k0 = 0; k0 < KD; k0 += 32) {
        gload_lds16(Ag0 + k0, sA0);
        gload_lds16(Ag1 + k0, sA1);
        gload_lds16(Bg0 + k0, sB0);
        gload_lds16(Bg1 + k0, sB1);
        __syncthreads();                    // compiler drains vmcnt before barrier
        bf16x8 a[4], b[4];
#pragma unroll
        for (int i = 0; i < 4; i++) a[i] = *(const bf16x8*)(sA + aOff[i]);
#pragma unroll
        for (int j = 0; j < 4; j++) b[j] = *(const bf16x8*)(sB + bOff[j]);
#pragma unroll
        for (int i = 0; i < 4; i++)
#pragma unroll
            for (int j = 0; j < 4; j++)
                acc[i][j] = __builtin_amdgcn_mfma_f32_16x16x32_bf16(a[i], b[j], acc[i][j], 0, 0, 0);
        __syncthreads();
    }

    // ---- epilogue (D: col=lo, row=q*4+rr)
#pragma unroll
    for (int i = 0; i < 4; i++) {
        int rowB = rowTile * 128 + wr * 64 + i * 16 + q * 4;
#pragma unroll
        for (int rr = 0; rr < 4; rr++) {
            int orow = rowB + rr;
            if (orow < n_e) {
                if (IS_FC) {
                    size_t hrow = (size_t)(ebase + orow);
#pragma unroll
                    for (int j = 0; j < 4; j++) {
                        float v = acc[i][j][rr];
                        v = 0.5f * v * (1.f + erff(v * 0.70710678118654752f));  // exact gelu
                        hmid[hrow * ND + n0 + wc * 64 + j * 16 + lo] = f2bf(v);
                    }
                } else {
                    int token = lst[orow] >> 1;
                    float g = gates[e * TOKENS + orow];
#pragma unroll
                    for (int j = 0; j < 4; j++) {
                        atomicAdd(&outp[(size_t)token * ND + n0 + wc * 64 + j * 16 + lo],
                                  acc[i][j][rr] * g);
                    }
                }
            }
        }
    }
}

// ---------------------------------------------------------------------------
extern "C" void kernel_launch(void* const* d_in, const int* in_sizes, int n_in,
                              void* d_out, int out_size, void* d_ws, size_t ws_size,
                              hipStream_t stream) {
    const float* x     = (const float*)d_in[0];   // [T, H]
    const float* gw    = (const float*)d_in[1];   // [E, H]
    const float* wfc   = (const float*)d_in[2];   // [E, FF, H]
    const float* wproj = (const float*)d_in[3];   // [E, H, FF]
    float* outp   = (float*)d_out;                       // [T*H]
    float* logits = outp + (size_t)TOKENS * HDIM;        // [T*E]

    char* ws = (char*)d_ws;
    int*   counts  = (int*)ws;                                   // 8 ints
    int*   bases   = (int*)(ws + 64);                            // 8 ints
    int*   entries = (int*)(ws + 256);                           // [E][T]
    float* gates   = (float*)(ws + 256 + NEXP * TOKENS * 4);     // [E][T]
    size_t off = 256 + 2ull * NEXP * TOKENS * 4;
    int*   tok_e   = (int*)(ws + off);   off += (size_t)TOKENS * 2 * 4;
    float* tok_g   = (float*)(ws + off); off += (size_t)TOKENS * 2 * 4;
    unsigned short* x_bf   = (unsigned short*)(ws + off); off += (size_t)TOKENS * HDIM * 2;
    unsigned short* wfc_bf = (unsigned short*)(ws + off); off += (size_t)NEXP * FFDIM * HDIM * 2;
    unsigned short* wpj_bf = (unsigned short*)(ws + off); off += (size_t)NEXP * HDIM * FFDIM * 2;
    unsigned short* hmid   = (unsigned short*)(ws + off);        // [2T][FF] bf16, slot-compacted

    zero_init<<<2048, 256, 0, stream>>>(outp, TOKENS * HDIM);
    cast_bf16<<<2048, 256, 0, stream>>>(wfc, wfc_bf, NEXP * FFDIM * HDIM / 4);
    cast_bf16<<<2048, 256, 0, stream>>>(wproj, wpj_bf, NEXP * HDIM * FFDIM / 4);
    gating<<<TOKENS / 4, 256, 0, stream>>>(x, gw, logits, tok_e, tok_g, x_bf);
    build_lists<<<1, 1024, 0, stream>>>(tok_e, tok_g, counts, bases, entries, gates);
    moe_gemm<HDIM, FFDIM, true ><<<dim3(FFDIM / 128, TOKENS / 128, NEXP), 256, 0, stream>>>(
        x_bf, wfc_bf, counts, bases, entries, gates, hmid, outp);
    moe_gemm<FFDIM, HDIM, false><<<dim3(HDIM / 128, TOKENS / 128, NEXP), 256, 0, stream>>>(
        hmid, wpj_bf, counts, bases, entries, gates, hmid, outp);
}